// Round 4
// baseline (430.790 us; speedup 1.0000x reference)
//
#include <hip/hip_runtime.h>
#include <stdint.h>

#define B_  16
#define V_  512
#define S_  1024
#define E_  8
#define FF_ 2048
#define NT_ (B_*V_)    // 8192 tokens (b,v)
#define NR_ (B_*S_)    // 16384 rows (b,s)

typedef __attribute__((ext_vector_type(8))) short bf16x8;   // 8 bf16 = 4 VGPRs
typedef __attribute__((ext_vector_type(4))) float f32x4;

__device__ __forceinline__ unsigned short f2bf(float f) {
    unsigned int u = __float_as_uint(f);
    u += 0x7FFFu + ((u >> 16) & 1u);          // round-to-nearest-even
    return (unsigned short)(u >> 16);
}
__device__ __forceinline__ float bf2f(unsigned short u) {
    return __uint_as_float(((unsigned int)u) << 16);
}

__device__ __forceinline__ void gl_lds16(const void* g, void* l) {
    // async global->LDS, 16B per lane; LDS dest = wave-uniform base + lane*16
    __builtin_amdgcn_global_load_lds((const __attribute__((address_space(1))) void*)g,
                                     (__attribute__((address_space(3))) void*)l,
                                     16, 0, 0);
}

// ---------------- fused fp32 -> bf16 convert for the three weight tensors ----------------
__device__ __forceinline__ void cvt4(const float* s, unsigned short* d, int i) {
    float4 v = *(const float4*)(s + i);
    ushort4 o; o.x = f2bf(v.x); o.y = f2bf(v.y); o.z = f2bf(v.z); o.w = f2bf(v.w);
    *(ushort4*)(d + i) = o;
}
__global__ void k_convert3(const float* __restrict__ s0, unsigned short* __restrict__ d0, int g0,
                           const float* __restrict__ s1, unsigned short* __restrict__ d1, int g1,
                           const float* __restrict__ s2, unsigned short* __restrict__ d2) {
    int g = blockIdx.x * 256 + threadIdx.x;
    if (g < g0)           cvt4(s0, d0, g * 4);
    else if (g < g0 + g1) cvt4(s1, d1, (g - g0) * 4);
    else                  cvt4(s2, d2, (g - g0 - g1) * 4);
}

// ---------------- x[B,S,V] -> xt_bf16[B,V,S] ----------------
__global__ void k_transpose_xt(const float* __restrict__ x, unsigned short* __restrict__ xt) {
    __shared__ float t[32][33];
    int b = blockIdx.z, st = blockIdx.y, vt = blockIdx.x;
    int col = threadIdx.x & 31, row8 = threadIdx.x >> 5;
    for (int r = 0; r < 4; ++r) {
        int sl = row8 + r * 8;
        t[sl][col] = x[(b * S_ + st * 32 + sl) * V_ + vt * 32 + col];
    }
    __syncthreads();
    for (int r = 0; r < 4; ++r) {
        int vl = row8 + r * 8;
        xt[(size_t)(b * V_ + vt * 32 + vl) * S_ + st * 32 + col] = f2bf(t[col][vl]);
    }
}

// ---------------- gating stage A: partial fp64 logits over 128-s chunks ----------------
__global__ __launch_bounds__(256) void k_gate_part(const float* __restrict__ x,
                                                   const float* __restrict__ gate_W,
                                                   double* __restrict__ part,
                                                   int* __restrict__ cnt) {
    __shared__ float gw[E_ * 128];         // 4 KB
    __shared__ double red[4 * 64 * E_];    // 16 KB
    int sc = blockIdx.x, vt0 = blockIdx.y * 64, b = blockIdx.z;
    int tid = threadIdx.x;
    if (sc == 0 && blockIdx.y == 0 && b == 0 && tid < E_) cnt[tid] = 0;
    for (int i = tid; i < E_ * 128; i += 256) {
        int e = i >> 7, j = i & 127;
        gw[i] = gate_W[e * S_ + sc * 128 + j];
    }
    __syncthreads();
    int vl = tid & 63, sg = tid >> 6;
    double acc[E_];
    #pragma unroll
    for (int e = 0; e < E_; ++e) acc[e] = 0.0;
    for (int jj = sg; jj < 128; jj += 4) {
        int s = sc * 128 + jj;
        double xv = (double)x[(b * S_ + s) * V_ + vt0 + vl];
        #pragma unroll
        for (int e = 0; e < E_; ++e) acc[e] += xv * (double)gw[e * 128 + jj];
    }
    #pragma unroll
    for (int e = 0; e < E_; ++e) red[(sg * 64 + vl) * E_ + e] = acc[e];
    __syncthreads();
    for (int i = tid; i < 64 * E_; i += 256) {
        int tkn = i >> 3, e = i & 7;
        double s = red[(0 * 64 + tkn) * E_ + e] + red[(1 * 64 + tkn) * E_ + e]
                 + red[(2 * 64 + tkn) * E_ + e] + red[(3 * 64 + tkn) * E_ + e];
        int t = b * V_ + vt0 + tkn;
        part[((size_t)sc * NT_ + t) * E_ + e] = s;
    }
}

// ---------------- gating stage B: reduce chunks, softmax, top-2, routing ----------------
__global__ __launch_bounds__(256) void k_gate_fin(const double* __restrict__ part,
                                                  float* __restrict__ probs_out,
                                                  int* __restrict__ cnt, int* __restrict__ tok_of,
                                                  int* __restrict__ tk_slot, float* __restrict__ tk_w) {
    int t = blockIdx.x * 256 + threadIdx.x;
    int lane = threadIdx.x & 63;
    double l[E_];
    #pragma unroll
    for (int e = 0; e < E_; ++e) l[e] = 0.0;
    for (int c = 0; c < S_ / 128; ++c) {
        const double* p = part + ((size_t)c * NT_ + t) * E_;
        #pragma unroll
        for (int e = 0; e < E_; ++e) l[e] += p[e];
    }
    double m = l[0];
    #pragma unroll
    for (int e = 1; e < E_; ++e) m = l[e] > m ? l[e] : m;
    double p[E_], sum = 0.0;
    #pragma unroll
    for (int e = 0; e < E_; ++e) { p[e] = exp(l[e] - m); sum += p[e]; }
    float pf[E_];
    #pragma unroll
    for (int e = 0; e < E_; ++e) pf[e] = (float)(p[e] / sum);
    float4 pa = {pf[0], pf[1], pf[2], pf[3]}, pb = {pf[4], pf[5], pf[6], pf[7]};
    *(float4*)(probs_out + (size_t)t * E_) = pa;
    *(float4*)(probs_out + (size_t)t * E_ + 4) = pb;
    int i0 = 0;
    #pragma unroll
    for (int e = 1; e < E_; ++e) if (pf[e] > pf[i0]) i0 = e;
    int i1 = -1;
    #pragma unroll
    for (int e = 0; e < E_; ++e) if (e != i0 && (i1 < 0 || pf[e] > pf[i1])) i1 = e;
    int sel[2] = {i0, i1};
    float wsel[2] = {pf[i0], pf[i1]};
    #pragma unroll
    for (int k = 0; k < 2; ++k) {
        int ie = sel[k];
        int pos = 0;
        for (int e = 0; e < E_; ++e) {                       // uniform loop, ballot legal
            unsigned long long msk = __ballot(ie == e);
            if (ie == e) {
                int rank = __popcll(msk & ((1ull << lane) - 1ull));
                int leader = __ffsll((long long)msk) - 1;
                int base = 0;
                if (lane == leader) base = atomicAdd(&cnt[e], __popcll(msk));
                base = __shfl(base, leader);
                pos = base + rank;
            }
        }
        tok_of[ie * NT_ + pos] = t;
        tk_slot[t * 2 + k] = (ie << 16) | pos;
        tk_w[t * 2 + k] = wsel[k];
    }
}

// ---------------- scan + build MoE tile table ----------------
__global__ void k_scan(const int* __restrict__ cnt, int* __restrict__ offs,
                       int* __restrict__ tile_hdr) {
    if (threadIdx.x == 0) {
        int o = 0, nt = 0;
        for (int e = 0; e < E_; ++e) {
            offs[e] = o;
            for (int p = 0; p < cnt[e]; p += 128) {
                tile_hdr[1 + nt * 2] = e;
                tile_hdr[2 + nt * 2] = p;
                ++nt;
            }
            o += cnt[e];
        }
        offs[E_] = o;
        tile_hdr[0] = nt;
    }
}

// ---------------- generalized GEMM K-loop: 128 x (TN*32) tile, BK=32 ----------------
// TN = MFMA n-tiles per wave. Waves 2x2: each wave computes 64 x (TN*16).
template<int TN>
__device__ __forceinline__ void gemm_k_loop_t(const unsigned short* a0, const unsigned short* a1,
                                              const unsigned short* (&bp)[TN / 2],
                                              short* As, short* Bs, int kIters, int wave, int lane,
                                              f32x4 (&acc)[4][TN]) {
    char* ldsA = (char*)As + wave * 2048;            // wave stages A rows [wave*32, +32)
    char* ldsB = (char*)Bs + wave * (TN / 2) * 1024; // wave stages B rows [wave*(TN*8), +TN*8)
    int wm = (wave & 1) << 6;
    int wn = (wave >> 1) * (TN * 16);
    int lr = lane & 15, quad = lane >> 4;
    for (int kk = 0; kk < kIters; ++kk) {
        gl_lds16(a0, ldsA);
        gl_lds16(a1, ldsA + 1024);
        #pragma unroll
        for (int c = 0; c < TN / 2; ++c) gl_lds16(bp[c], ldsB + c * 1024);
        a0 += 32; a1 += 32;
        #pragma unroll
        for (int c = 0; c < TN / 2; ++c) bp[c] += 32;
        __syncthreads();                    // drains vmcnt before LDS reads
        bf16x8 af[4], bfv[TN];
        #pragma unroll
        for (int i = 0; i < 4; ++i)
            af[i] = *(const bf16x8*)(As + (wm + i * 16 + lr) * 32 + quad * 8);
        #pragma unroll
        for (int j = 0; j < TN; ++j)
            bfv[j] = *(const bf16x8*)(Bs + (wn + j * 16 + lr) * 32 + quad * 8);
        #pragma unroll
        for (int i = 0; i < 4; ++i)
            #pragma unroll
            for (int j = 0; j < TN; ++j)
                acc[i][j] = __builtin_amdgcn_mfma_f32_16x16x32_bf16(af[i], bfv[j], acc[i][j], 0, 0, 0);
        __syncthreads();
    }
}

// ---------------- MoE gather-GEMM: 128x256 tiles (TN=8) ----------------
__global__ __launch_bounds__(256) void k_moe_gemm(const unsigned short* __restrict__ xt,
                                                  const unsigned short* __restrict__ expWb,
                                                  const float* __restrict__ exp_b,
                                                  const int* __restrict__ cnt, const int* __restrict__ offs,
                                                  const int* __restrict__ tok_of,
                                                  const int* __restrict__ tile_hdr,
                                                  unsigned short* __restrict__ Yb) {
    int ntl = tile_hdr[0];
    if ((int)blockIdx.x >= ntl) return;
    int e    = tile_hdr[1 + blockIdx.x * 2];
    int pos0 = tile_hdr[2 + blockIdx.x * 2];
    int ne = cnt[e];
    int n0 = blockIdx.y * 256;
    __shared__ __align__(16) short As[128 * 32];   //  8 KB
    __shared__ __align__(16) short Bs[256 * 32];   // 16 KB
    int tid = threadIdx.x, wave = tid >> 6, lane = tid & 63;
    int rA0 = wave * 32 + (lane >> 2);
    int rA1 = rA0 + 16;
    int koff = (lane & 3) * 8;
    int tok0 = tok_of[e * NT_ + min(pos0 + rA0, ne - 1)];
    int tok1 = tok_of[e * NT_ + min(pos0 + rA1, ne - 1)];
    const unsigned short* a0 = xt + (size_t)tok0 * S_ + koff;
    const unsigned short* a1 = xt + (size_t)tok1 * S_ + koff;
    const unsigned short* Wb = expWb + (size_t)e * S_ * S_;
    const unsigned short* bp[4];
    #pragma unroll
    for (int c = 0; c < 4; ++c)
        bp[c] = Wb + (size_t)(n0 + wave * 64 + c * 16 + (lane >> 2)) * S_ + koff;
    f32x4 acc[4][8] = {};
    gemm_k_loop_t<8>(a0, a1, bp, As, Bs, S_ / 32, wave, lane, acc);
    int wm = (wave & 1) << 6, wn = (wave >> 1) << 7;
    int lr = lane & 15, quad = lane >> 4;
    int yrow0 = offs[e];
    #pragma unroll
    for (int i = 0; i < 4; ++i)
        #pragma unroll
        for (int r = 0; r < 4; ++r) {
            int pos = pos0 + wm + i * 16 + quad * 4 + r;
            if (pos < ne) {
                size_t row = (size_t)(yrow0 + pos);
                #pragma unroll
                for (int j = 0; j < 8; ++j) {
                    int col = n0 + wn + j * 16 + lr;
                    Yb[row * S_ + col] = f2bf(acc[i][j][r] + exp_b[e * S_ + col]);
                }
            }
        }
}

// ---------------- combine: x2b[b,s,v] = bf16(x + relu(w0*Y0 + w1*Y1)) ----------------
__global__ void k_combine(const float* __restrict__ x, const unsigned short* __restrict__ Yb,
                          const int* __restrict__ offs, const int* __restrict__ tk_slot,
                          const float* __restrict__ tk_w,
                          unsigned short* __restrict__ x2b) {
    __shared__ float t[32][33];
    int b = blockIdx.z, st = blockIdx.y, vt = blockIdx.x;
    int tid = threadIdx.x;
    int vl = tid >> 3, sq = (tid & 7) * 4;
    int tok = b * V_ + vt * 32 + vl;
    int s0 = tk_slot[tok * 2 + 0], s1 = tk_slot[tok * 2 + 1];
    float w0 = tk_w[tok * 2 + 0], w1 = tk_w[tok * 2 + 1];
    size_t r0 = (size_t)(offs[s0 >> 16] + (s0 & 0xFFFF));
    size_t r1 = (size_t)(offs[s1 >> 16] + (s1 & 0xFFFF));
    int sg = st * 32 + sq;
    ushort4 y0 = *(const ushort4*)(Yb + r0 * S_ + sg);
    ushort4 y1 = *(const ushort4*)(Yb + r1 * S_ + sg);
    t[vl][sq + 0] = fmaxf(w0 * bf2f(y0.x) + w1 * bf2f(y1.x), 0.f);
    t[vl][sq + 1] = fmaxf(w0 * bf2f(y0.y) + w1 * bf2f(y1.y), 0.f);
    t[vl][sq + 2] = fmaxf(w0 * bf2f(y0.z) + w1 * bf2f(y1.z), 0.f);
    t[vl][sq + 3] = fmaxf(w0 * bf2f(y0.w) + w1 * bf2f(y1.w), 0.f);
    __syncthreads();
    int vcol = tid & 31, srow8 = tid >> 5;
    for (int r = 0; r < 4; ++r) {
        int sl = srow8 + r * 8;
        size_t gi = (size_t)(b * S_ + st * 32 + sl) * V_ + vt * 32 + vcol;
        x2b[gi] = f2bf(x[gi] + t[vcol][sl]);
    }
}

// ---------------- fc1: h = relu(x2b @ fc1W^T + b) -> bf16, 128x256 tiles ----------------
__global__ __launch_bounds__(256) void k_fc1(const unsigned short* __restrict__ x2b,
                                             const unsigned short* __restrict__ w1b,
                                             const float* __restrict__ fc1_b,
                                             unsigned short* __restrict__ h) {
    __shared__ __align__(16) short As[128 * 32];
    __shared__ __align__(16) short Bs[256 * 32];
    int tid = threadIdx.x, wave = tid >> 6, lane = tid & 63;
    int rA0 = wave * 32 + (lane >> 2), rA1 = rA0 + 16;
    int koff = (lane & 3) * 8;
    int m0 = blockIdx.x * 128, n0 = blockIdx.y * 256;
    const unsigned short* a0 = x2b + (size_t)(m0 + rA0) * V_ + koff;
    const unsigned short* a1 = x2b + (size_t)(m0 + rA1) * V_ + koff;
    const unsigned short* bp[4];
    #pragma unroll
    for (int c = 0; c < 4; ++c)
        bp[c] = w1b + (size_t)(n0 + wave * 64 + c * 16 + (lane >> 2)) * V_ + koff;
    f32x4 acc[4][8] = {};
    gemm_k_loop_t<8>(a0, a1, bp, As, Bs, V_ / 32, wave, lane, acc);
    int wm = (wave & 1) << 6, wn = (wave >> 1) << 7;
    int lr = lane & 15, quad = lane >> 4;
    #pragma unroll
    for (int i = 0; i < 4; ++i)
        #pragma unroll
        for (int r = 0; r < 4; ++r) {
            size_t row = (size_t)(m0 + wm + i * 16 + quad * 4 + r);
            #pragma unroll
            for (int j = 0; j < 8; ++j) {
                int col = n0 + wn + j * 16 + lr;
                h[row * FF_ + col] = f2bf(fmaxf(acc[i][j][r] + fc1_b[col], 0.f));
            }
        }
}

// ---------------- fc2: out = h @ fc2W^T + b + x2b (residual), 128x128 tiles ----------------
__global__ __launch_bounds__(256) void k_fc2(const unsigned short* __restrict__ h,
                                             const unsigned short* __restrict__ w2b,
                                             const float* __restrict__ fc2_b,
                                             const unsigned short* __restrict__ x2b,
                                             float* __restrict__ out) {
    __shared__ __align__(16) short As[128 * 32];
    __shared__ __align__(16) short Bs[128 * 32];
    int tid = threadIdx.x, wave = tid >> 6, lane = tid & 63;
    int rA0 = wave * 32 + (lane >> 2), rA1 = rA0 + 16;
    int koff = (lane & 3) * 8;
    int m0 = blockIdx.x * 128, n0 = blockIdx.y * 128;
    const unsigned short* a0 = h + (size_t)(m0 + rA0) * FF_ + koff;
    const unsigned short* a1 = h + (size_t)(m0 + rA1) * FF_ + koff;
    const unsigned short* bp[2];
    #pragma unroll
    for (int c = 0; c < 2; ++c)
        bp[c] = w2b + (size_t)(n0 + wave * 32 + c * 16 + (lane >> 2)) * FF_ + koff;
    f32x4 acc[4][4] = {};
    gemm_k_loop_t<4>(a0, a1, bp, As, Bs, FF_ / 32, wave, lane, acc);
    int wm = (wave & 1) << 6, wn = (wave >> 1) << 6;
    int lr = lane & 15, quad = lane >> 4;
    #pragma unroll
    for (int i = 0; i < 4; ++i)
        #pragma unroll
        for (int r = 0; r < 4; ++r) {
            size_t row = (size_t)(m0 + wm + i * 16 + quad * 4 + r);
            #pragma unroll
            for (int j = 0; j < 4; ++j) {
                int col = n0 + wn + j * 16 + lr;
                out[row * V_ + col] = acc[i][j][r] + fc2_b[col] + bf2f(x2b[row * V_ + col]);
            }
        }
}

extern "C" void kernel_launch(void* const* d_in, const int* in_sizes, int n_in,
                              void* d_out, int out_size, void* d_ws, size_t ws_size,
                              hipStream_t stream) {
    const float* x      = (const float*)d_in[0];
    const float* gate_W = (const float*)d_in[1];
    const float* exp_W  = (const float*)d_in[2];
    const float* exp_b  = (const float*)d_in[3];
    const float* fc1_W  = (const float*)d_in[4];
    const float* fc1_b  = (const float*)d_in[5];
    const float* fc2_W  = (const float*)d_in[6];
    const float* fc2_b  = (const float*)d_in[7];
    float* out_x = (float*)d_out;
    float* out_p = (float*)d_out + (size_t)B_ * S_ * V_;

    if (ws_size < (size_t)155582592) return;

    char* ws = (char*)d_ws;
    unsigned short* Yb    = (unsigned short*)(ws);             // 33.5 MB used (region 67 MB)
    unsigned short* xt    = (unsigned short*)(ws +  67108864); // 16.7 MB
    int*            tile_hdr = (int*)(ws + 83886080);          // in freed region
    unsigned short* x2b   = (unsigned short*)(ws + 117440512); // 16.7 MB
    unsigned short* expWb = (unsigned short*)(ws + 134217728); // 16.7 MB
    unsigned short* fc1Wb = (unsigned short*)(ws + 150994944); //  2 MB
    unsigned short* fc2Wb = (unsigned short*)(ws + 153092096); //  2 MB
    char* route = ws + 155189248;
    int*   cnt     = (int*)(route);
    int*   offs    = (int*)(route + 64);
    int*   tok_of  = (int*)(route + 128);
    int*   tk_slot = (int*)(route + 128 + 262144);
    float* tk_w    = (float*)(route + 128 + 262144 + 65536);
    unsigned short* h = (unsigned short*)ws;   // alias: Yb dead after k_combine; h = 67 MB
    double* part = (double*)ws;                // alias: gate partials (4 MB) dead before k_moe_gemm

    // weight converts fused: expW 2097152 float4-groups, fc1W 262144, fc2W 262144
    k_convert3<<<dim3((2097152 + 262144 + 262144) / 256), 256, 0, stream>>>(
        exp_W, expWb, 2097152, fc1_W, fc1Wb, 262144, fc2_W, fc2Wb);
    k_transpose_xt<<<dim3(V_ / 32, S_ / 32, B_), 256, 0, stream>>>(x, xt);
    k_gate_part<<<dim3(S_ / 128, V_ / 64, B_), 256, 0, stream>>>(x, gate_W, part, cnt);
    k_gate_fin<<<dim3(NT_ / 256), 256, 0, stream>>>(part, out_p, cnt, tok_of, tk_slot, tk_w);
    k_scan<<<1, 64, 0, stream>>>(cnt, offs, tile_hdr);
    k_moe_gemm<<<dim3(135, S_ / 256), 256, 0, stream>>>(xt, expWb, exp_b, cnt, offs, tok_of, tile_hdr, Yb);
    k_combine<<<dim3(V_ / 32, S_ / 32, B_), 256, 0, stream>>>(x, Yb, offs, tk_slot, tk_w, x2b);
    k_fc1<<<dim3(NR_ / 128, FF_ / 256), 256, 0, stream>>>(x2b, fc1Wb, fc1_b, h);
    k_fc2<<<dim3(NR_ / 128, V_ / 128), 256, 0, stream>>>(h, fc2Wb, fc2_b, x2b, out_x);
}

// Round 5
// 369.381 us; speedup vs baseline: 1.1662x; 1.1662x over previous
//
#include <hip/hip_runtime.h>
#include <stdint.h>

#define B_  16
#define V_  512
#define S_  1024
#define E_  8
#define FF_ 2048
#define NT_ (B_*V_)    // 8192 tokens (b,v)
#define NR_ (B_*S_)    // 16384 rows (b,s)

typedef __attribute__((ext_vector_type(8))) short bf16x8;    // 8 bf16 = 4 VGPRs
typedef __attribute__((ext_vector_type(16))) float f32x16;   // 32x32 MFMA acc

__device__ __forceinline__ unsigned short f2bf(float f) {
    unsigned int u = __float_as_uint(f);
    u += 0x7FFFu + ((u >> 16) & 1u);          // round-to-nearest-even
    return (unsigned short)(u >> 16);
}
__device__ __forceinline__ float bf2f(unsigned short u) {
    return __uint_as_float(((unsigned int)u) << 16);
}

__device__ __forceinline__ void gl_lds16(const void* g, void* l) {
    // async global->LDS, 16B per lane; LDS dest = wave-uniform base + lane*16
    __builtin_amdgcn_global_load_lds((const __attribute__((address_space(1))) void*)g,
                                     (__attribute__((address_space(3))) void*)l,
                                     16, 0, 0);
}

// ---------------- fused fp32 -> bf16 convert for the three weight tensors ----------------
__device__ __forceinline__ void cvt4(const float* s, unsigned short* d, int i) {
    float4 v = *(const float4*)(s + i);
    ushort4 o; o.x = f2bf(v.x); o.y = f2bf(v.y); o.z = f2bf(v.z); o.w = f2bf(v.w);
    *(ushort4*)(d + i) = o;
}
__global__ void k_convert3(const float* __restrict__ s0, unsigned short* __restrict__ d0, int g0,
                           const float* __restrict__ s1, unsigned short* __restrict__ d1, int g1,
                           const float* __restrict__ s2, unsigned short* __restrict__ d2) {
    int g = blockIdx.x * 256 + threadIdx.x;
    if (g < g0)           cvt4(s0, d0, g * 4);
    else if (g < g0 + g1) cvt4(s1, d1, (g - g0) * 4);
    else                  cvt4(s2, d2, (g - g0 - g1) * 4);
}

// ---------------- x[B,S,V] -> xt_bf16[B,V,S] ----------------
__global__ void k_transpose_xt(const float* __restrict__ x, unsigned short* __restrict__ xt) {
    __shared__ float t[32][33];
    int b = blockIdx.z, st = blockIdx.y, vt = blockIdx.x;
    int col = threadIdx.x & 31, row8 = threadIdx.x >> 5;
    for (int r = 0; r < 4; ++r) {
        int sl = row8 + r * 8;
        t[sl][col] = x[(b * S_ + st * 32 + sl) * V_ + vt * 32 + col];
    }
    __syncthreads();
    for (int r = 0; r < 4; ++r) {
        int vl = row8 + r * 8;
        xt[(size_t)(b * V_ + vt * 32 + vl) * S_ + st * 32 + col] = f2bf(t[col][vl]);
    }
}

// ---------------- gating stage A: partial fp64 logits over 128-s chunks ----------------
__global__ __launch_bounds__(256) void k_gate_part(const float* __restrict__ x,
                                                   const float* __restrict__ gate_W,
                                                   double* __restrict__ part,
                                                   int* __restrict__ cnt) {
    __shared__ float gw[E_ * 128];         // 4 KB
    __shared__ double red[4 * 64 * E_];    // 16 KB
    int sc = blockIdx.x, vt0 = blockIdx.y * 64, b = blockIdx.z;
    int tid = threadIdx.x;
    if (sc == 0 && blockIdx.y == 0 && b == 0 && tid < E_) cnt[tid] = 0;
    for (int i = tid; i < E_ * 128; i += 256) {
        int e = i >> 7, j = i & 127;
        gw[i] = gate_W[e * S_ + sc * 128 + j];
    }
    __syncthreads();
    int vl = tid & 63, sg = tid >> 6;
    double acc[E_];
    #pragma unroll
    for (int e = 0; e < E_; ++e) acc[e] = 0.0;
    for (int jj = sg; jj < 128; jj += 4) {
        int s = sc * 128 + jj;
        double xv = (double)x[(b * S_ + s) * V_ + vt0 + vl];
        #pragma unroll
        for (int e = 0; e < E_; ++e) acc[e] += xv * (double)gw[e * 128 + jj];
    }
    #pragma unroll
    for (int e = 0; e < E_; ++e) red[(sg * 64 + vl) * E_ + e] = acc[e];
    __syncthreads();
    for (int i = tid; i < 64 * E_; i += 256) {
        int tkn = i >> 3, e = i & 7;
        double s = red[(0 * 64 + tkn) * E_ + e] + red[(1 * 64 + tkn) * E_ + e]
                 + red[(2 * 64 + tkn) * E_ + e] + red[(3 * 64 + tkn) * E_ + e];
        int t = b * V_ + vt0 + tkn;
        part[((size_t)sc * NT_ + t) * E_ + e] = s;
    }
}

// ---------------- gating stage B: reduce chunks, softmax, top-2, routing ----------------
__global__ __launch_bounds__(256) void k_gate_fin(const double* __restrict__ part,
                                                  float* __restrict__ probs_out,
                                                  int* __restrict__ cnt, int* __restrict__ tok_of,
                                                  int* __restrict__ tk_slot, float* __restrict__ tk_w) {
    int t = blockIdx.x * 256 + threadIdx.x;
    int lane = threadIdx.x & 63;
    double l[E_];
    #pragma unroll
    for (int e = 0; e < E_; ++e) l[e] = 0.0;
    for (int c = 0; c < S_ / 128; ++c) {
        const double* p = part + ((size_t)c * NT_ + t) * E_;
        #pragma unroll
        for (int e = 0; e < E_; ++e) l[e] += p[e];
    }
    double m = l[0];
    #pragma unroll
    for (int e = 1; e < E_; ++e) m = l[e] > m ? l[e] : m;
    double p[E_], sum = 0.0;
    #pragma unroll
    for (int e = 0; e < E_; ++e) { p[e] = exp(l[e] - m); sum += p[e]; }
    float pf[E_];
    #pragma unroll
    for (int e = 0; e < E_; ++e) pf[e] = (float)(p[e] / sum);
    float4 pa = {pf[0], pf[1], pf[2], pf[3]}, pb = {pf[4], pf[5], pf[6], pf[7]};
    *(float4*)(probs_out + (size_t)t * E_) = pa;
    *(float4*)(probs_out + (size_t)t * E_ + 4) = pb;
    int i0 = 0;
    #pragma unroll
    for (int e = 1; e < E_; ++e) if (pf[e] > pf[i0]) i0 = e;
    int i1 = -1;
    #pragma unroll
    for (int e = 0; e < E_; ++e) if (e != i0 && (i1 < 0 || pf[e] > pf[i1])) i1 = e;
    int sel[2] = {i0, i1};
    float wsel[2] = {pf[i0], pf[i1]};
    #pragma unroll
    for (int k = 0; k < 2; ++k) {
        int ie = sel[k];
        int pos = 0;
        for (int e = 0; e < E_; ++e) {                       // uniform loop, ballot legal
            unsigned long long msk = __ballot(ie == e);
            if (ie == e) {
                int rank = __popcll(msk & ((1ull << lane) - 1ull));
                int leader = __ffsll((long long)msk) - 1;
                int base = 0;
                if (lane == leader) base = atomicAdd(&cnt[e], __popcll(msk));
                base = __shfl(base, leader);
                pos = base + rank;
            }
        }
        tok_of[ie * NT_ + pos] = t;
        tk_slot[t * 2 + k] = (ie << 16) | pos;
        tk_w[t * 2 + k] = wsel[k];
    }
}

// ---------------- scan + build MoE tile table ----------------
__global__ void k_scan(const int* __restrict__ cnt, int* __restrict__ offs,
                       int* __restrict__ tile_hdr) {
    if (threadIdx.x == 0) {
        int o = 0, nt = 0;
        for (int e = 0; e < E_; ++e) {
            offs[e] = o;
            for (int p = 0; p < cnt[e]; p += 128) {
                tile_hdr[1 + nt * 2] = e;
                tile_hdr[2 + nt * 2] = p;
                ++nt;
            }
            o += cnt[e];
        }
        offs[E_] = o;
        tile_hdr[0] = nt;
    }
}

// ---------------- GEMM K-loop, 128x128 tile, BK=32, 32x32x16 MFMA ----------------
// 4 waves 2x2; each wave computes 64x64 as 2x2 tiles of 32x32. acc = 4 x f32x16 = 64 AGPR.
// Frags live per k-step: 2 A + 2 B = 16 VGPR.
__device__ __forceinline__ void gemm_k_loop32(const unsigned short* a0, const unsigned short* a1,
                                              const unsigned short* b0, const unsigned short* b1,
                                              short* As, short* Bs, int kIters, int wave, int lane,
                                              f32x16 (&acc)[2][2]) {
    char* ldsA = (char*)As + wave * 2048;   // wave stages A rows [wave*32, +32)
    char* ldsB = (char*)Bs + wave * 2048;
    int wm = (wave & 1) << 6, wn = (wave >> 1) << 6;
    int l31 = lane & 31, h8 = (lane >> 5) * 8;
    for (int kk = 0; kk < kIters; ++kk) {
        gl_lds16(a0, ldsA);
        gl_lds16(a1, ldsA + 1024);
        gl_lds16(b0, ldsB);
        gl_lds16(b1, ldsB + 1024);
        a0 += 32; a1 += 32; b0 += 32; b1 += 32;
        __syncthreads();                    // drains vmcnt before LDS reads
        #pragma unroll
        for (int ks = 0; ks < 2; ++ks) {
            bf16x8 af0 = *(const bf16x8*)(As + (wm + l31) * 32 + ks * 16 + h8);
            bf16x8 af1 = *(const bf16x8*)(As + (wm + 32 + l31) * 32 + ks * 16 + h8);
            bf16x8 bg0 = *(const bf16x8*)(Bs + (wn + l31) * 32 + ks * 16 + h8);
            bf16x8 bg1 = *(const bf16x8*)(Bs + (wn + 32 + l31) * 32 + ks * 16 + h8);
            acc[0][0] = __builtin_amdgcn_mfma_f32_32x32x16_bf16(af0, bg0, acc[0][0], 0, 0, 0);
            acc[0][1] = __builtin_amdgcn_mfma_f32_32x32x16_bf16(af0, bg1, acc[0][1], 0, 0, 0);
            acc[1][0] = __builtin_amdgcn_mfma_f32_32x32x16_bf16(af1, bg0, acc[1][0], 0, 0, 0);
            acc[1][1] = __builtin_amdgcn_mfma_f32_32x32x16_bf16(af1, bg1, acc[1][1], 0, 0, 0);
        }
        __syncthreads();
    }
}

// C/D layout (HW-verified m74/m101): col = lane&31, row = (reg&3) + 8*(reg>>2) + 4*(lane>>5)

// ---------------- MoE gather-GEMM: Yb = bf16(xt[tok] @ expW[e]^T + exp_b) ----------------
__global__ __launch_bounds__(256, 4) void k_moe_gemm(const unsigned short* __restrict__ xt,
                                                     const unsigned short* __restrict__ expWb,
                                                     const float* __restrict__ exp_b,
                                                     const int* __restrict__ cnt, const int* __restrict__ offs,
                                                     const int* __restrict__ tok_of,
                                                     const int* __restrict__ tile_hdr,
                                                     unsigned short* __restrict__ Yb) {
    int ntl = tile_hdr[0];
    if ((int)blockIdx.x >= ntl) return;
    int e    = tile_hdr[1 + blockIdx.x * 2];
    int pos0 = tile_hdr[2 + blockIdx.x * 2];
    int ne = cnt[e];
    int nt = blockIdx.y;
    __shared__ __align__(16) short As[128 * 32];
    __shared__ __align__(16) short Bs[128 * 32];
    int tid = threadIdx.x, wave = tid >> 6, lane = tid & 63;
    int rA0 = wave * 32 + (lane >> 2);
    int rA1 = rA0 + 16;
    int koff = (lane & 3) * 8;
    int tok0 = tok_of[e * NT_ + min(pos0 + rA0, ne - 1)];
    int tok1 = tok_of[e * NT_ + min(pos0 + rA1, ne - 1)];
    const unsigned short* a0 = xt + (size_t)tok0 * S_ + koff;
    const unsigned short* a1 = xt + (size_t)tok1 * S_ + koff;
    const unsigned short* Wb = expWb + (size_t)e * S_ * S_;
    const unsigned short* b0 = Wb + (size_t)(nt * 128 + rA0) * S_ + koff;
    const unsigned short* b1 = Wb + (size_t)(nt * 128 + rA1) * S_ + koff;
    f32x16 acc[2][2] = {};
    gemm_k_loop32(a0, a1, b0, b1, As, Bs, S_ / 32, wave, lane, acc);
    int wm = (wave & 1) << 6, wn = (wave >> 1) << 6;
    int l31 = lane & 31, half4 = (lane >> 5) * 4;
    int yrow0 = offs[e];
    #pragma unroll
    for (int mi = 0; mi < 2; ++mi)
        #pragma unroll
        for (int reg = 0; reg < 16; ++reg) {
            int pos = pos0 + wm + mi * 32 + (reg & 3) + 8 * (reg >> 2) + half4;
            if (pos < ne) {
                size_t row = (size_t)(yrow0 + pos);
                #pragma unroll
                for (int nj = 0; nj < 2; ++nj) {
                    int col = nt * 128 + wn + nj * 32 + l31;
                    Yb[row * S_ + col] = f2bf(acc[mi][nj][reg] + exp_b[e * S_ + col]);
                }
            }
        }
}

// ---------------- combine: x2b[b,s,v] = bf16(x + relu(w0*Y0 + w1*Y1)) ----------------
__global__ void k_combine(const float* __restrict__ x, const unsigned short* __restrict__ Yb,
                          const int* __restrict__ offs, const int* __restrict__ tk_slot,
                          const float* __restrict__ tk_w,
                          unsigned short* __restrict__ x2b) {
    __shared__ float t[32][33];
    int b = blockIdx.z, st = blockIdx.y, vt = blockIdx.x;
    int tid = threadIdx.x;
    int vl = tid >> 3, sq = (tid & 7) * 4;
    int tok = b * V_ + vt * 32 + vl;
    int s0 = tk_slot[tok * 2 + 0], s1 = tk_slot[tok * 2 + 1];
    float w0 = tk_w[tok * 2 + 0], w1 = tk_w[tok * 2 + 1];
    size_t r0 = (size_t)(offs[s0 >> 16] + (s0 & 0xFFFF));
    size_t r1 = (size_t)(offs[s1 >> 16] + (s1 & 0xFFFF));
    int sg = st * 32 + sq;
    ushort4 y0 = *(const ushort4*)(Yb + r0 * S_ + sg);
    ushort4 y1 = *(const ushort4*)(Yb + r1 * S_ + sg);
    t[vl][sq + 0] = fmaxf(w0 * bf2f(y0.x) + w1 * bf2f(y1.x), 0.f);
    t[vl][sq + 1] = fmaxf(w0 * bf2f(y0.y) + w1 * bf2f(y1.y), 0.f);
    t[vl][sq + 2] = fmaxf(w0 * bf2f(y0.z) + w1 * bf2f(y1.z), 0.f);
    t[vl][sq + 3] = fmaxf(w0 * bf2f(y0.w) + w1 * bf2f(y1.w), 0.f);
    __syncthreads();
    int vcol = tid & 31, srow8 = tid >> 5;
    for (int r = 0; r < 4; ++r) {
        int sl = srow8 + r * 8;
        size_t gi = (size_t)(b * S_ + st * 32 + sl) * V_ + vt * 32 + vcol;
        x2b[gi] = f2bf(x[gi] + t[vcol][sl]);
    }
}

// ---------------- fc1: h = relu(x2b @ fc1W^T + b) -> bf16 ----------------
__global__ __launch_bounds__(256, 4) void k_fc1(const unsigned short* __restrict__ x2b,
                                                const unsigned short* __restrict__ w1b,
                                                const float* __restrict__ fc1_b,
                                                unsigned short* __restrict__ h) {
    __shared__ __align__(16) short As[128 * 32];
    __shared__ __align__(16) short Bs[128 * 32];
    int tid = threadIdx.x, wave = tid >> 6, lane = tid & 63;
    int rA0 = wave * 32 + (lane >> 2), rA1 = rA0 + 16;
    int koff = (lane & 3) * 8;
    int m0 = blockIdx.x * 128, n0 = blockIdx.y * 128;
    const unsigned short* a0 = x2b + (size_t)(m0 + rA0) * V_ + koff;
    const unsigned short* a1 = x2b + (size_t)(m0 + rA1) * V_ + koff;
    const unsigned short* b0 = w1b + (size_t)(n0 + rA0) * V_ + koff;
    const unsigned short* b1 = w1b + (size_t)(n0 + rA1) * V_ + koff;
    f32x16 acc[2][2] = {};
    gemm_k_loop32(a0, a1, b0, b1, As, Bs, V_ / 32, wave, lane, acc);
    int wm = (wave & 1) << 6, wn = (wave >> 1) << 6;
    int l31 = lane & 31, half4 = (lane >> 5) * 4;
    #pragma unroll
    for (int mi = 0; mi < 2; ++mi)
        #pragma unroll
        for (int reg = 0; reg < 16; ++reg) {
            size_t row = (size_t)(m0 + wm + mi * 32 + (reg & 3) + 8 * (reg >> 2) + half4);
            #pragma unroll
            for (int nj = 0; nj < 2; ++nj) {
                int col = n0 + wn + nj * 32 + l31;
                h[row * FF_ + col] = f2bf(fmaxf(acc[mi][nj][reg] + fc1_b[col], 0.f));
            }
        }
}

// ---------------- fc2: out = h @ fc2W^T + b + x2b (residual) ----------------
__global__ __launch_bounds__(256) void k_fc2(const unsigned short* __restrict__ h,
                                             const unsigned short* __restrict__ w2b,
                                             const float* __restrict__ fc2_b,
                                             const unsigned short* __restrict__ x2b,
                                             float* __restrict__ out) {
    __shared__ __align__(16) short As[128 * 32];
    __shared__ __align__(16) short Bs[128 * 32];
    int tid = threadIdx.x, wave = tid >> 6, lane = tid & 63;
    int rA0 = wave * 32 + (lane >> 2), rA1 = rA0 + 16;
    int koff = (lane & 3) * 8;
    int m0 = blockIdx.x * 128, n0 = blockIdx.y * 128;
    const unsigned short* a0 = h + (size_t)(m0 + rA0) * FF_ + koff;
    const unsigned short* a1 = h + (size_t)(m0 + rA1) * FF_ + koff;
    const unsigned short* b0 = w2b + (size_t)(n0 + rA0) * FF_ + koff;
    const unsigned short* b1 = w2b + (size_t)(n0 + rA1) * FF_ + koff;
    f32x16 acc[2][2] = {};
    gemm_k_loop32(a0, a1, b0, b1, As, Bs, FF_ / 32, wave, lane, acc);
    int wm = (wave & 1) << 6, wn = (wave >> 1) << 6;
    int l31 = lane & 31, half4 = (lane >> 5) * 4;
    #pragma unroll
    for (int mi = 0; mi < 2; ++mi)
        #pragma unroll
        for (int reg = 0; reg < 16; ++reg) {
            size_t row = (size_t)(m0 + wm + mi * 32 + (reg & 3) + 8 * (reg >> 2) + half4);
            #pragma unroll
            for (int nj = 0; nj < 2; ++nj) {
                int col = n0 + wn + nj * 32 + l31;
                out[row * V_ + col] = acc[mi][nj][reg] + fc2_b[col] + bf2f(x2b[row * V_ + col]);
            }
        }
}

extern "C" void kernel_launch(void* const* d_in, const int* in_sizes, int n_in,
                              void* d_out, int out_size, void* d_ws, size_t ws_size,
                              hipStream_t stream) {
    const float* x      = (const float*)d_in[0];
    const float* gate_W = (const float*)d_in[1];
    const float* exp_W  = (const float*)d_in[2];
    const float* exp_b  = (const float*)d_in[3];
    const float* fc1_W  = (const float*)d_in[4];
    const float* fc1_b  = (const float*)d_in[5];
    const float* fc2_W  = (const float*)d_in[6];
    const float* fc2_b  = (const float*)d_in[7];
    float* out_x = (float*)d_out;
    float* out_p = (float*)d_out + (size_t)B_ * S_ * V_;

    if (ws_size < (size_t)155582592) return;

    char* ws = (char*)d_ws;
    unsigned short* Yb    = (unsigned short*)(ws);             // 33.5 MB used (region 67 MB)
    unsigned short* xt    = (unsigned short*)(ws +  67108864); // 16.7 MB
    int*            tile_hdr = (int*)(ws + 83886080);          // in freed region
    unsigned short* x2b   = (unsigned short*)(ws + 117440512); // 16.7 MB
    unsigned short* expWb = (unsigned short*)(ws + 134217728); // 16.7 MB
    unsigned short* fc1Wb = (unsigned short*)(ws + 150994944); //  2 MB
    unsigned short* fc2Wb = (unsigned short*)(ws + 153092096); //  2 MB
    char* route = ws + 155189248;
    int*   cnt     = (int*)(route);
    int*   offs    = (int*)(route + 64);
    int*   tok_of  = (int*)(route + 128);
    int*   tk_slot = (int*)(route + 128 + 262144);
    float* tk_w    = (float*)(route + 128 + 262144 + 65536);
    unsigned short* h = (unsigned short*)ws;   // alias: Yb dead after k_combine; h = 67 MB
    double* part = (double*)ws;                // alias: gate partials (4 MB) dead before k_moe_gemm

    // weight converts fused: expW 2097152 float4-groups, fc1W 262144, fc2W 262144
    k_convert3<<<dim3((2097152 + 262144 + 262144) / 256), 256, 0, stream>>>(
        exp_W, expWb, 2097152, fc1_W, fc1Wb, 262144, fc2_W, fc2Wb);
    k_transpose_xt<<<dim3(V_ / 32, S_ / 32, B_), 256, 0, stream>>>(x, xt);
    k_gate_part<<<dim3(S_ / 128, V_ / 64, B_), 256, 0, stream>>>(x, gate_W, part, cnt);
    k_gate_fin<<<dim3(NT_ / 256), 256, 0, stream>>>(part, out_p, cnt, tok_of, tk_slot, tk_w);
    k_scan<<<1, 64, 0, stream>>>(cnt, offs, tile_hdr);
    k_moe_gemm<<<dim3(136, S_ / 128), 256, 0, stream>>>(xt, expWb, exp_b, cnt, offs, tok_of, tile_hdr, Yb);
    k_combine<<<dim3(V_ / 32, S_ / 32, B_), 256, 0, stream>>>(x, Yb, offs, tk_slot, tk_w, x2b);
    k_fc1<<<dim3(NR_ / 128, FF_ / 128), 256, 0, stream>>>(x2b, fc1Wb, fc1_b, h);
    k_fc2<<<dim3(NR_ / 128, V_ / 128), 256, 0, stream>>>(h, fc2Wb, fc2_b, x2b, out_x);
}

// Round 6
// 342.966 us; speedup vs baseline: 1.2561x; 1.0770x over previous
//
#include <hip/hip_runtime.h>
#include <stdint.h>

#define B_  16
#define V_  512
#define S_  1024
#define E_  8
#define FF_ 2048
#define NT_ (B_*V_)    // 8192 tokens (b,v)
#define NR_ (B_*S_)    // 16384 rows (b,s)

typedef __attribute__((ext_vector_type(8))) short bf16x8;   // 8 bf16 = 4 VGPRs
typedef __attribute__((ext_vector_type(4))) float f32x4;

__device__ __forceinline__ unsigned short f2bf(float f) {
    unsigned int u = __float_as_uint(f);
    u += 0x7FFFu + ((u >> 16) & 1u);          // round-to-nearest-even
    return (unsigned short)(u >> 16);
}
__device__ __forceinline__ float bf2f(unsigned short u) {
    return __uint_as_float(((unsigned int)u) << 16);
}

__device__ __forceinline__ void gl_lds16(const void* g, void* l) {
    // async global->LDS, 16B per lane; LDS dest = wave-uniform base + lane*16
    __builtin_amdgcn_global_load_lds((const __attribute__((address_space(1))) void*)g,
                                     (__attribute__((address_space(3))) void*)l,
                                     16, 0, 0);
}

// ---------------- fused fp32 -> bf16 convert for the three weight tensors ----------------
__device__ __forceinline__ void cvt4(const float* s, unsigned short* d, int i) {
    float4 v = *(const float4*)(s + i);
    ushort4 o; o.x = f2bf(v.x); o.y = f2bf(v.y); o.z = f2bf(v.z); o.w = f2bf(v.w);
    *(ushort4*)(d + i) = o;
}
__global__ void k_convert3(const float* __restrict__ s0, unsigned short* __restrict__ d0, int g0,
                           const float* __restrict__ s1, unsigned short* __restrict__ d1, int g1,
                           const float* __restrict__ s2, unsigned short* __restrict__ d2) {
    int g = blockIdx.x * 256 + threadIdx.x;
    if (g < g0)           cvt4(s0, d0, g * 4);
    else if (g < g0 + g1) cvt4(s1, d1, (g - g0) * 4);
    else                  cvt4(s2, d2, (g - g0 - g1) * 4);
}

// ---------------- x[B,S,V] -> xt_bf16[B,V,S] ----------------
__global__ void k_transpose_xt(const float* __restrict__ x, unsigned short* __restrict__ xt) {
    __shared__ float t[32][33];
    int b = blockIdx.z, st = blockIdx.y, vt = blockIdx.x;
    int col = threadIdx.x & 31, row8 = threadIdx.x >> 5;
    for (int r = 0; r < 4; ++r) {
        int sl = row8 + r * 8;
        t[sl][col] = x[(b * S_ + st * 32 + sl) * V_ + vt * 32 + col];
    }
    __syncthreads();
    for (int r = 0; r < 4; ++r) {
        int vl = row8 + r * 8;
        xt[(size_t)(b * V_ + vt * 32 + vl) * S_ + st * 32 + col] = f2bf(t[col][vl]);
    }
}

// ---------------- gating stage A: partial fp64 logits over 128-s chunks ----------------
__global__ __launch_bounds__(256) void k_gate_part(const float* __restrict__ x,
                                                   const float* __restrict__ gate_W,
                                                   double* __restrict__ part,
                                                   int* __restrict__ cnt) {
    __shared__ float gw[E_ * 128];         // 4 KB
    __shared__ double red[4 * 64 * E_];    // 16 KB
    int sc = blockIdx.x, vt0 = blockIdx.y * 64, b = blockIdx.z;
    int tid = threadIdx.x;
    if (sc == 0 && blockIdx.y == 0 && b == 0 && tid < E_) cnt[tid] = 0;
    for (int i = tid; i < E_ * 128; i += 256) {
        int e = i >> 7, j = i & 127;
        gw[i] = gate_W[e * S_ + sc * 128 + j];
    }
    __syncthreads();
    int vl = tid & 63, sg = tid >> 6;
    double acc[E_];
    #pragma unroll
    for (int e = 0; e < E_; ++e) acc[e] = 0.0;
    for (int jj = sg; jj < 128; jj += 4) {
        int s = sc * 128 + jj;
        double xv = (double)x[(b * S_ + s) * V_ + vt0 + vl];
        #pragma unroll
        for (int e = 0; e < E_; ++e) acc[e] += xv * (double)gw[e * 128 + jj];
    }
    #pragma unroll
    for (int e = 0; e < E_; ++e) red[(sg * 64 + vl) * E_ + e] = acc[e];
    __syncthreads();
    for (int i = tid; i < 64 * E_; i += 256) {
        int tkn = i >> 3, e = i & 7;
        double s = red[(0 * 64 + tkn) * E_ + e] + red[(1 * 64 + tkn) * E_ + e]
                 + red[(2 * 64 + tkn) * E_ + e] + red[(3 * 64 + tkn) * E_ + e];
        int t = b * V_ + vt0 + tkn;
        part[((size_t)sc * NT_ + t) * E_ + e] = s;
    }
}

// ---------------- gating stage B: reduce chunks, softmax, top-2, routing ----------------
__global__ __launch_bounds__(256) void k_gate_fin(const double* __restrict__ part,
                                                  float* __restrict__ probs_out,
                                                  int* __restrict__ cnt, int* __restrict__ tok_of,
                                                  int* __restrict__ tk_slot, float* __restrict__ tk_w) {
    int t = blockIdx.x * 256 + threadIdx.x;
    int lane = threadIdx.x & 63;
    double l[E_];
    #pragma unroll
    for (int e = 0; e < E_; ++e) l[e] = 0.0;
    for (int c = 0; c < S_ / 128; ++c) {
        const double* p = part + ((size_t)c * NT_ + t) * E_;
        #pragma unroll
        for (int e = 0; e < E_; ++e) l[e] += p[e];
    }
    double m = l[0];
    #pragma unroll
    for (int e = 1; e < E_; ++e) m = l[e] > m ? l[e] : m;
    double p[E_], sum = 0.0;
    #pragma unroll
    for (int e = 0; e < E_; ++e) { p[e] = exp(l[e] - m); sum += p[e]; }
    float pf[E_];
    #pragma unroll
    for (int e = 0; e < E_; ++e) pf[e] = (float)(p[e] / sum);
    float4 pa = {pf[0], pf[1], pf[2], pf[3]}, pb = {pf[4], pf[5], pf[6], pf[7]};
    *(float4*)(probs_out + (size_t)t * E_) = pa;
    *(float4*)(probs_out + (size_t)t * E_ + 4) = pb;
    int i0 = 0;
    #pragma unroll
    for (int e = 1; e < E_; ++e) if (pf[e] > pf[i0]) i0 = e;
    int i1 = -1;
    #pragma unroll
    for (int e = 0; e < E_; ++e) if (e != i0 && (i1 < 0 || pf[e] > pf[i1])) i1 = e;
    int sel[2] = {i0, i1};
    float wsel[2] = {pf[i0], pf[i1]};
    #pragma unroll
    for (int k = 0; k < 2; ++k) {
        int ie = sel[k];
        int pos = 0;
        for (int e = 0; e < E_; ++e) {                       // uniform loop, ballot legal
            unsigned long long msk = __ballot(ie == e);
            if (ie == e) {
                int rank = __popcll(msk & ((1ull << lane) - 1ull));
                int leader = __ffsll((long long)msk) - 1;
                int base = 0;
                if (lane == leader) base = atomicAdd(&cnt[e], __popcll(msk));
                base = __shfl(base, leader);
                pos = base + rank;
            }
        }
        tok_of[ie * NT_ + pos] = t;
        tk_slot[t * 2 + k] = (ie << 16) | pos;
        tk_w[t * 2 + k] = wsel[k];
    }
}

// ---------------- scan + build MoE tile table ----------------
__global__ void k_scan(const int* __restrict__ cnt, int* __restrict__ offs,
                       int* __restrict__ tile_hdr) {
    if (threadIdx.x == 0) {
        int o = 0, nt = 0;
        for (int e = 0; e < E_; ++e) {
            offs[e] = o;
            for (int p = 0; p < cnt[e]; p += 128) {
                tile_hdr[1 + nt * 2] = e;
                tile_hdr[2 + nt * 2] = p;
                ++nt;
            }
            o += cnt[e];
        }
        offs[E_] = o;
        tile_hdr[0] = nt;
    }
}

// ---------------- GEMM K-loop: 128x128 tile, BK=64, 16x16x32 MFMA, XOR-swizzled LDS ----------------
// LDS row = 64 shorts (128 B). Global 16B-chunk c of row R stored at position p = c ^ (R&7).
// Stager (per wave, 4 instrs): rows wave*32 + c*8 + (lane>>3), global chunk (lane&7)^((lane>>3)&7).
// Reader: chunk c = quad + 4*ks  ->  offset = ((quad ^ (lr&7))*8) ^ (32*ks)  [shorts].
// Bank check: chunk-group (addr/16B) mod 8 = (quad+4ks)^(lr&7) -> uniform 8 lanes/group = b128 floor.
__device__ __forceinline__ void gemm_k_loop64(const unsigned short* (&ap)[4],
                                              const unsigned short* (&bp)[4],
                                              short* As, short* Bs, int kIters, int wave, int lane,
                                              f32x4 (&acc)[4][4]) {
    char* ldsA = (char*)As + wave * 4096;   // wave stages A rows [wave*32, +32): 4 instrs x 1 KB
    char* ldsB = (char*)Bs + wave * 4096;
    int wm = (wave & 1) << 6, wn = (wave >> 1) << 6;
    int lr = lane & 15, quad = lane >> 4;
    int pb = (quad ^ (lr & 7)) * 8;         // swizzled chunk offset for ks=0 (in shorts)
    const unsigned short* a0 = ap[0]; const unsigned short* a1 = ap[1];
    const unsigned short* a2 = ap[2]; const unsigned short* a3 = ap[3];
    const unsigned short* b0 = bp[0]; const unsigned short* b1 = bp[1];
    const unsigned short* b2 = bp[2]; const unsigned short* b3 = bp[3];
    for (int kk = 0; kk < kIters; ++kk) {
        gl_lds16(a0, ldsA);        gl_lds16(a1, ldsA + 1024);
        gl_lds16(a2, ldsA + 2048); gl_lds16(a3, ldsA + 3072);
        gl_lds16(b0, ldsB);        gl_lds16(b1, ldsB + 1024);
        gl_lds16(b2, ldsB + 2048); gl_lds16(b3, ldsB + 3072);
        a0 += 64; a1 += 64; a2 += 64; a3 += 64;
        b0 += 64; b1 += 64; b2 += 64; b3 += 64;
        __syncthreads();                    // drains vmcnt before LDS reads
        #pragma unroll
        for (int ks = 0; ks < 2; ++ks) {
            int po = pb ^ (ks << 5);
            bf16x8 af[4], bfv[4];
            #pragma unroll
            for (int i = 0; i < 4; ++i)
                af[i] = *(const bf16x8*)(As + (wm + i * 16 + lr) * 64 + po);
            #pragma unroll
            for (int j = 0; j < 4; ++j)
                bfv[j] = *(const bf16x8*)(Bs + (wn + j * 16 + lr) * 64 + po);
            #pragma unroll
            for (int i = 0; i < 4; ++i)
                #pragma unroll
                for (int j = 0; j < 4; ++j)
                    acc[i][j] = __builtin_amdgcn_mfma_f32_16x16x32_bf16(af[i], bfv[j], acc[i][j], 0, 0, 0);
        }
        __syncthreads();
    }
}

// ---------------- MoE gather-GEMM: Yb = bf16(xt[tok] @ expW[e]^T + exp_b) ----------------
__global__ __launch_bounds__(256, 3) void k_moe_gemm(const unsigned short* __restrict__ xt,
                                                     const unsigned short* __restrict__ expWb,
                                                     const float* __restrict__ exp_b,
                                                     const int* __restrict__ cnt, const int* __restrict__ offs,
                                                     const int* __restrict__ tok_of,
                                                     const int* __restrict__ tile_hdr,
                                                     unsigned short* __restrict__ Yb) {
    int ntl = tile_hdr[0];
    if ((int)blockIdx.x >= ntl) return;
    int e    = tile_hdr[1 + blockIdx.x * 2];
    int pos0 = tile_hdr[2 + blockIdx.x * 2];
    int ne = cnt[e];
    int nt = blockIdx.y;
    __shared__ __align__(16) short As[128 * 64];   // 16 KB
    __shared__ __align__(16) short Bs[128 * 64];   // 16 KB
    int tid = threadIdx.x, wave = tid >> 6, lane = tid & 63;
    int rowLoc = wave * 32 + (lane >> 3);          // + c*8 per staging instr
    int cg = ((lane & 7) ^ ((lane >> 3) & 7)) * 8; // swizzled source chunk offset (shorts)
    const unsigned short* Wb = expWb + (size_t)e * S_ * S_;
    const unsigned short* ap[4];
    const unsigned short* bp[4];
    #pragma unroll
    for (int c = 0; c < 4; ++c) {
        int rr = rowLoc + c * 8;
        int tok = tok_of[e * NT_ + min(pos0 + rr, ne - 1)];
        ap[c] = xt + (size_t)tok * S_ + cg;
        bp[c] = Wb + (size_t)(nt * 128 + rr) * S_ + cg;
    }
    f32x4 acc[4][4] = {};
    gemm_k_loop64(ap, bp, As, Bs, S_ / 64, wave, lane, acc);
    int wm = (wave & 1) << 6, wn = (wave >> 1) << 6;
    int lr = lane & 15, quad = lane >> 4;
    int yrow0 = offs[e];
    #pragma unroll
    for (int i = 0; i < 4; ++i)
        #pragma unroll
        for (int r = 0; r < 4; ++r) {
            int pos = pos0 + wm + i * 16 + quad * 4 + r;
            if (pos < ne) {
                size_t row = (size_t)(yrow0 + pos);
                #pragma unroll
                for (int j = 0; j < 4; ++j) {
                    int col = nt * 128 + wn + j * 16 + lr;
                    Yb[row * S_ + col] = f2bf(acc[i][j][r] + exp_b[e * S_ + col]);
                }
            }
        }
}

// ---------------- combine: x2b[b,s,v] = bf16(x + relu(w0*Y0 + w1*Y1)) ----------------
__global__ void k_combine(const float* __restrict__ x, const unsigned short* __restrict__ Yb,
                          const int* __restrict__ offs, const int* __restrict__ tk_slot,
                          const float* __restrict__ tk_w,
                          unsigned short* __restrict__ x2b) {
    __shared__ float t[32][33];
    int b = blockIdx.z, st = blockIdx.y, vt = blockIdx.x;
    int tid = threadIdx.x;
    int vl = tid >> 3, sq = (tid & 7) * 4;
    int tok = b * V_ + vt * 32 + vl;
    int s0 = tk_slot[tok * 2 + 0], s1 = tk_slot[tok * 2 + 1];
    float w0 = tk_w[tok * 2 + 0], w1 = tk_w[tok * 2 + 1];
    size_t r0 = (size_t)(offs[s0 >> 16] + (s0 & 0xFFFF));
    size_t r1 = (size_t)(offs[s1 >> 16] + (s1 & 0xFFFF));
    int sg = st * 32 + sq;
    ushort4 y0 = *(const ushort4*)(Yb + r0 * S_ + sg);
    ushort4 y1 = *(const ushort4*)(Yb + r1 * S_ + sg);
    t[vl][sq + 0] = fmaxf(w0 * bf2f(y0.x) + w1 * bf2f(y1.x), 0.f);
    t[vl][sq + 1] = fmaxf(w0 * bf2f(y0.y) + w1 * bf2f(y1.y), 0.f);
    t[vl][sq + 2] = fmaxf(w0 * bf2f(y0.z) + w1 * bf2f(y1.z), 0.f);
    t[vl][sq + 3] = fmaxf(w0 * bf2f(y0.w) + w1 * bf2f(y1.w), 0.f);
    __syncthreads();
    int vcol = tid & 31, srow8 = tid >> 5;
    for (int r = 0; r < 4; ++r) {
        int sl = srow8 + r * 8;
        size_t gi = (size_t)(b * S_ + st * 32 + sl) * V_ + vt * 32 + vcol;
        x2b[gi] = f2bf(x[gi] + t[vcol][sl]);
    }
}

// ---------------- fc1: h = relu(x2b @ fc1W^T + b) -> bf16 ----------------
__global__ __launch_bounds__(256, 3) void k_fc1(const unsigned short* __restrict__ x2b,
                                                const unsigned short* __restrict__ w1b,
                                                const float* __restrict__ fc1_b,
                                                unsigned short* __restrict__ h) {
    __shared__ __align__(16) short As[128 * 64];
    __shared__ __align__(16) short Bs[128 * 64];
    int tid = threadIdx.x, wave = tid >> 6, lane = tid & 63;
    int rowLoc = wave * 32 + (lane >> 3);
    int cg = ((lane & 7) ^ ((lane >> 3) & 7)) * 8;
    int m0 = blockIdx.x * 128, n0 = blockIdx.y * 128;
    const unsigned short* ap[4];
    const unsigned short* bp[4];
    #pragma unroll
    for (int c = 0; c < 4; ++c) {
        int rr = rowLoc + c * 8;
        ap[c] = x2b + (size_t)(m0 + rr) * V_ + cg;
        bp[c] = w1b + (size_t)(n0 + rr) * V_ + cg;
    }
    f32x4 acc[4][4] = {};
    gemm_k_loop64(ap, bp, As, Bs, V_ / 64, wave, lane, acc);
    int wm = (wave & 1) << 6, wn = (wave >> 1) << 6;
    int lr = lane & 15, quad = lane >> 4;
    #pragma unroll
    for (int i = 0; i < 4; ++i)
        #pragma unroll
        for (int r = 0; r < 4; ++r) {
            size_t row = (size_t)(m0 + wm + i * 16 + quad * 4 + r);
            #pragma unroll
            for (int j = 0; j < 4; ++j) {
                int col = n0 + wn + j * 16 + lr;
                h[row * FF_ + col] = f2bf(fmaxf(acc[i][j][r] + fc1_b[col], 0.f));
            }
        }
}

// ---------------- fc2: out = h @ fc2W^T + b + x2b (residual) ----------------
__global__ __launch_bounds__(256, 3) void k_fc2(const unsigned short* __restrict__ h,
                                                const unsigned short* __restrict__ w2b,
                                                const float* __restrict__ fc2_b,
                                                const unsigned short* __restrict__ x2b,
                                                float* __restrict__ out) {
    __shared__ __align__(16) short As[128 * 64];
    __shared__ __align__(16) short Bs[128 * 64];
    int tid = threadIdx.x, wave = tid >> 6, lane = tid & 63;
    int rowLoc = wave * 32 + (lane >> 3);
    int cg = ((lane & 7) ^ ((lane >> 3) & 7)) * 8;
    int m0 = blockIdx.x * 128, n0 = blockIdx.y * 128;
    const unsigned short* ap[4];
    const unsigned short* bp[4];
    #pragma unroll
    for (int c = 0; c < 4; ++c) {
        int rr = rowLoc + c * 8;
        ap[c] = h + (size_t)(m0 + rr) * FF_ + cg;
        bp[c] = w2b + (size_t)(n0 + rr) * FF_ + cg;
    }
    f32x4 acc[4][4] = {};
    gemm_k_loop64(ap, bp, As, Bs, FF_ / 64, wave, lane, acc);
    int wm = (wave & 1) << 6, wn = (wave >> 1) << 6;
    int lr = lane & 15, quad = lane >> 4;
    #pragma unroll
    for (int i = 0; i < 4; ++i)
        #pragma unroll
        for (int r = 0; r < 4; ++r) {
            size_t row = (size_t)(m0 + wm + i * 16 + quad * 4 + r);
            #pragma unroll
            for (int j = 0; j < 4; ++j) {
                int col = n0 + wn + j * 16 + lr;
                out[row * V_ + col] = acc[i][j][r] + fc2_b[col] + bf2f(x2b[row * V_ + col]);
            }
        }
}

extern "C" void kernel_launch(void* const* d_in, const int* in_sizes, int n_in,
                              void* d_out, int out_size, void* d_ws, size_t ws_size,
                              hipStream_t stream) {
    const float* x      = (const float*)d_in[0];
    const float* gate_W = (const float*)d_in[1];
    const float* exp_W  = (const float*)d_in[2];
    const float* exp_b  = (const float*)d_in[3];
    const float* fc1_W  = (const float*)d_in[4];
    const float* fc1_b  = (const float*)d_in[5];
    const float* fc2_W  = (const float*)d_in[6];
    const float* fc2_b  = (const float*)d_in[7];
    float* out_x = (float*)d_out;
    float* out_p = (float*)d_out + (size_t)B_ * S_ * V_;

    if (ws_size < (size_t)155582592) return;

    char* ws = (char*)d_ws;
    unsigned short* Yb    = (unsigned short*)(ws);             // 33.5 MB used (region 67 MB)
    unsigned short* xt    = (unsigned short*)(ws +  67108864); // 16.7 MB
    int*            tile_hdr = (int*)(ws + 83886080);          // in freed region
    unsigned short* x2b   = (unsigned short*)(ws + 117440512); // 16.7 MB
    unsigned short* expWb = (unsigned short*)(ws + 134217728); // 16.7 MB
    unsigned short* fc1Wb = (unsigned short*)(ws + 150994944); //  2 MB
    unsigned short* fc2Wb = (unsigned short*)(ws + 153092096); //  2 MB
    char* route = ws + 155189248;
    int*   cnt     = (int*)(route);
    int*   offs    = (int*)(route + 64);
    int*   tok_of  = (int*)(route + 128);
    int*   tk_slot = (int*)(route + 128 + 262144);
    float* tk_w    = (float*)(route + 128 + 262144 + 65536);
    unsigned short* h = (unsigned short*)ws;   // alias: Yb dead after k_combine; h = 67 MB
    double* part = (double*)ws;                // alias: gate partials (4 MB) dead before k_moe_gemm

    // weight converts fused: expW 2097152 float4-groups, fc1W 262144, fc2W 262144
    k_convert3<<<dim3((2097152 + 262144 + 262144) / 256), 256, 0, stream>>>(
        exp_W, expWb, 2097152, fc1_W, fc1Wb, 262144, fc2_W, fc2Wb);
    k_transpose_xt<<<dim3(V_ / 32, S_ / 32, B_), 256, 0, stream>>>(x, xt);
    k_gate_part<<<dim3(S_ / 128, V_ / 64, B_), 256, 0, stream>>>(x, gate_W, part, cnt);
    k_gate_fin<<<dim3(NT_ / 256), 256, 0, stream>>>(part, out_p, cnt, tok_of, tk_slot, tk_w);
    k_scan<<<1, 64, 0, stream>>>(cnt, offs, tile_hdr);
    k_moe_gemm<<<dim3(136, S_ / 128), 256, 0, stream>>>(xt, expWb, exp_b, cnt, offs, tok_of, tile_hdr, Yb);
    k_combine<<<dim3(V_ / 32, S_ / 32, B_), 256, 0, stream>>>(x, Yb, offs, tk_slot, tk_w, x2b);
    k_fc1<<<dim3(NR_ / 128, FF_ / 128), 256, 0, stream>>>(x2b, fc1Wb, fc1_b, h);
    k_fc2<<<dim3(NR_ / 128, V_ / 128), 256, 0, stream>>>(h, fc2Wb, fc2_b, x2b, out_x);
}